// Round 2
// baseline (128.990 us; speedup 1.0000x reference)
//
#include <hip/hip_runtime.h>
#include <hip/hip_bf16.h>
#include <cstdint>
#include <cstddef>

typedef __attribute__((ext_vector_type(8))) short bf16x8;
typedef __attribute__((ext_vector_type(4))) float f32x4;

#define BATCH 8
#define NTOK 8192
#define LDIM 512
#define DDIM 128
#define NQ 16
#define NSEG 8
#define SEGLEN (NTOK / NSEG) /* 1024 */

static __device__ __forceinline__ short f2bf(float f) {
  union { float f; uint32_t u; } v; v.f = f;
  uint32_t u = v.u;
  uint32_t r = u + 0x7fffu + ((u >> 16) & 1u); // RNE
  return (short)(r >> 16);
}

// pad-mask accessor robust to bool-ABI (byteFlag=1: 1B/elem, 0: int32/elem)
static __device__ __forceinline__ bool is_pad(const void* pad, int byteFlag, int j) {
  return byteFlag ? (((const unsigned char*)pad)[j] != 0)
                  : (((const int*)pad)[j] != 0);
}

// ---------------- detect: is key_pad_mask byte-packed or int32? ----------------
// Scan first 64KB as u32 (valid under both layouts: 64KB = whole buffer if bytes,
// first quarter if int32). If byte-packed, packed bool patterns give values >1
// with probability 1-0.729^16384 ~= 1. If int32, all values are 0/1.
__global__ __launch_bounds__(256) void k_detect(const unsigned int* __restrict__ pad_raw,
                                                int* __restrict__ flag) {
  int any_gt1 = 0;
  for (int i = threadIdx.x; i < 16384; i += 256)
    if (pad_raw[i] > 1u) any_gt1 = 1;
  unsigned long long m = __ballot(any_gt1);
  __shared__ int s[4];
  if ((threadIdx.x & 63) == 0) s[threadIdx.x >> 6] = (m != 0ull) ? 1 : 0;
  __syncthreads();
  if (threadIdx.x == 0) flag[0] = (s[0] | s[1] | s[2] | s[3]);
}

// ---------------- k0: repack W1 [512][128] fp32 -> MFMA B-fragment order bf16 ----------------
// wfrag[(c*8 + t)*64 + lane][i] = bf16( W1[c*32 + (lane>>4)*8 + i][t*16 + (lane&15)] )
__global__ void k0_wfrag(const float* __restrict__ W1, short* __restrict__ wfrag) {
  int tid = blockIdx.x * blockDim.x + threadIdx.x; // 8192 threads: (c, t, lane)
  if (tid >= 16 * 8 * 64) return;
  int l = tid & 63;
  int t = (tid >> 6) & 7;
  int c = tid >> 9;
  int kbase = c * 32 + (l >> 4) * 8;
  int col = t * 16 + (l & 15);
  bf16x8 frag;
#pragma unroll
  for (int i = 0; i < 8; ++i) frag[i] = f2bf(W1[(size_t)(kbase + i) * DDIM + col]);
  ((bf16x8*)wfrag)[tid] = frag;
}

// ---------------- k1: scores A[r] = tanh(x[r,:] @ W1) @ W2 ----------------
__global__ __launch_bounds__(256) void k1_scores(const float* __restrict__ x,
                                                 const short* __restrict__ wfrag,
                                                 const float* __restrict__ W2,
                                                 float* __restrict__ A) {
  int wave = threadIdx.x >> 6, lane = threadIdx.x & 63;
  int rowBase = blockIdx.x * 64 + wave * 16;
  const float* xrow = x + (size_t)(rowBase + (lane & 15)) * LDIM + ((lane >> 4) * 8);
  const bf16x8* wf = ((const bf16x8*)wfrag) + lane;

  f32x4 acc[8];
#pragma unroll
  for (int t = 0; t < 8; ++t) acc[t] = (f32x4){0.f, 0.f, 0.f, 0.f};

  for (int c = 0; c < 16; ++c) {
    float4 a0 = *(const float4*)(xrow + c * 32);
    float4 a1 = *(const float4*)(xrow + c * 32 + 4);
    bf16x8 af;
    af[0] = f2bf(a0.x); af[1] = f2bf(a0.y); af[2] = f2bf(a0.z); af[3] = f2bf(a0.w);
    af[4] = f2bf(a1.x); af[5] = f2bf(a1.y); af[6] = f2bf(a1.z); af[7] = f2bf(a1.w);
    const bf16x8* wfc = wf + c * 512;
#pragma unroll
    for (int t = 0; t < 8; ++t)
      acc[t] = __builtin_amdgcn_mfma_f32_16x16x32_bf16(af, wfc[t * 64], acc[t], 0, 0, 0);
  }

  // epilogue: tanh + dot W2; D layout: col = lane&15 (+16t), row = (lane>>4)*4 + r
  float asum[4] = {0.f, 0.f, 0.f, 0.f};
#pragma unroll
  for (int t = 0; t < 8; ++t) {
    float w2v = W2[t * 16 + (lane & 15)];
#pragma unroll
    for (int r = 0; r < 4; ++r) {
      float h = 1.f - 2.f / (__expf(2.f * acc[t][r]) + 1.f); // tanh
      asum[r] += h * w2v;
    }
  }
#pragma unroll
  for (int m = 1; m < 16; m <<= 1) {
#pragma unroll
    for (int r = 0; r < 4; ++r) asum[r] += __shfl_xor(asum[r], m, 64);
  }
  if ((lane & 15) == 0) {
    int rb = rowBase + (lane >> 4) * 4;
#pragma unroll
    for (int r = 0; r < 4; ++r) A[rb + r] = asum[r];
  }
}

// ---------------- k2: per-(b,q) softmax stats (max, 1/sumexp) ----------------
__global__ __launch_bounds__(256) void k2_stats(const float* __restrict__ A,
                                                const int* __restrict__ ids,
                                                const void* __restrict__ pad,
                                                const int* __restrict__ flag,
                                                float* __restrict__ stats) {
  int b = blockIdx.x >> 4, q = blockIdx.x & 15;
  int tid = threadIdx.x;
  int bf = flag[0];
  __shared__ float red[4];
  const int base = b * NTOK;

  float mx = -3.4e38f;
  for (int j = tid; j < NTOK; j += 256) {
    bool mem = (ids[base + j] == q) && !is_pad(pad, bf, base + j);
    if (mem) mx = fmaxf(mx, A[base + j]);
  }
#pragma unroll
  for (int m = 1; m < 64; m <<= 1) mx = fmaxf(mx, __shfl_xor(mx, m, 64));
  if ((tid & 63) == 0) red[tid >> 6] = mx;
  __syncthreads();
  mx = fmaxf(fmaxf(red[0], red[1]), fmaxf(red[2], red[3]));

  float s = 0.f;
  for (int j = tid; j < NTOK; j += 256) {
    bool mem = (ids[base + j] == q) && !is_pad(pad, bf, base + j);
    if (mem) s += __expf(A[base + j] - mx);
  }
#pragma unroll
  for (int m = 1; m < 64; m <<= 1) s += __shfl_xor(s, m, 64);
  __syncthreads();
  if ((tid & 63) == 0) red[tid >> 6] = s;
  __syncthreads();
  if (tid == 0) {
    float st = red[0] + red[1] + red[2] + red[3];
    stats[blockIdx.x * 2] = mx;
    stats[blockIdx.x * 2 + 1] = (st > 0.f) ? (1.f / st) : 0.f;
  }
}

// ---------------- k3: weighted pooling partials ----------------
__global__ __launch_bounds__(256) void k3_pool(const float* __restrict__ x,
                                               const float* __restrict__ A,
                                               const int* __restrict__ ids,
                                               const void* __restrict__ pad,
                                               const int* __restrict__ flag,
                                               const float* __restrict__ stats,
                                               float* __restrict__ partial) {
  int blk = blockIdx.x;
  int s = blk & 7, q = (blk >> 3) & 15, b = blk >> 7;
  int wave = threadIdx.x >> 6, lane = threadIdx.x & 63;
  int bfl = flag[0];
  __shared__ float w_lds[1024];
  __shared__ unsigned short j_lds[1024];
  __shared__ int cnt[4];

  float mx = stats[(b * 16 + q) * 2];
  float invs = stats[(b * 16 + q) * 2 + 1];
  const int base = b * NTOK;

  int wbase = wave * 256;
  int wpos = wbase;
#pragma unroll
  for (int g = 0; g < 4; ++g) {
    int j = s * SEGLEN + wave * 256 + g * 64 + lane;
    bool mem = (ids[base + j] == q) && !is_pad(pad, bfl, base + j);
    float wt = mem ? __expf(A[base + j] - mx) * invs : 0.f;
    unsigned long long mask = __ballot(mem);
    if (mem) {
      int pos = wpos + __popcll(mask & ((1ull << lane) - 1ull));
      w_lds[pos] = wt;
      j_lds[pos] = (unsigned short)j;
    }
    wpos += __popcll(mask);
  }
  if (lane == 0) cnt[wave] = wpos - wbase;
  __syncthreads();

  int c0 = threadIdx.x * 2;
  float ax = 0.f, ay = 0.f;
  for (int w = 0; w < 4; ++w) {
    int nw = cnt[w];
    for (int e = 0; e < nw; ++e) {
      float wt = w_lds[w * 256 + e];
      int j = j_lds[w * 256 + e];
      const float* xr = x + (size_t)(base + j) * LDIM + c0;
      ax += wt * xr[0];
      ay += wt * xr[1];
    }
  }
  size_t po = (size_t)blk * LDIM + c0; // partial[b][q][s][c]
  partial[po] = ax;
  partial[po + 1] = ay;
}

// ---------------- k4: reduce partials over segments -> out ----------------
__global__ void k4_reduce(const float* __restrict__ partial, float* __restrict__ out) {
  int e = blockIdx.x * blockDim.x + threadIdx.x;
  if (e >= BATCH * NQ * LDIM) return;
  int bi = e >> 9, c = e & 511;
  float sum = 0.f;
#pragma unroll
  for (int t = 0; t < 8; ++t) sum += partial[(size_t)(bi * 8 + t) * LDIM + c];
  out[e] = sum;
}

extern "C" void kernel_launch(void* const* d_in, const int* in_sizes, int n_in,
                              void* d_out, int out_size, void* d_ws, size_t ws_size,
                              hipStream_t stream) {
  const float* x = (const float*)d_in[0];
  const float* W1 = (const float*)d_in[1];
  const float* W2 = (const float*)d_in[2];
  const int* ids = (const int*)d_in[3];
  const void* pad = d_in[4]; // bool ABI unknown: byte-packed or int32 (detected)
  float* out = (float*)d_out;

  char* ws = (char*)d_ws;
  short* wfrag = (short*)ws;                                // 128 KB
  float* A = (float*)(ws + 131072);                         // 256 KB
  float* stats = (float*)(ws + 131072 + 262144);            // 1 KB
  float* partial = (float*)(ws + 131072 + 262144 + 1024);   // 2 MB
  int* flag = (int*)(ws + 131072 + 262144 + 1024 + 2097152);

  hipLaunchKernelGGL(k_detect, dim3(1), dim3(256), 0, stream, (const unsigned int*)pad, flag);
  hipLaunchKernelGGL(k0_wfrag, dim3(32), dim3(256), 0, stream, W1, wfrag);
  hipLaunchKernelGGL(k1_scores, dim3((BATCH * NTOK) / 64), dim3(256), 0, stream, x, wfrag, W2, A);
  hipLaunchKernelGGL(k2_stats, dim3(BATCH * NQ), dim3(256), 0, stream, A, ids, pad, flag, stats);
  hipLaunchKernelGGL(k3_pool, dim3(BATCH * NQ * NSEG), dim3(256), 0, stream, x, A, ids, pad, flag, stats, partial);
  hipLaunchKernelGGL(k4_reduce, dim3((BATCH * NQ * LDIM) / 256), dim3(256), 0, stream, partial, out);
}

// Round 3
// 117.199 us; speedup vs baseline: 1.1006x; 1.1006x over previous
//
#include <hip/hip_runtime.h>
#include <hip/hip_bf16.h>
#include <cstdint>
#include <cstddef>

typedef __attribute__((ext_vector_type(8))) short bf16x8;
typedef __attribute__((ext_vector_type(4))) float f32x4;

#define BATCH 8
#define NTOK 8192
#define LDIM 512
#define DDIM 128
#define NQ 16
#define NSEG 8
#define SEGLEN (NTOK / NSEG) /* 1024 */

static __device__ __forceinline__ short f2bf(float f) {
  uint32_t u = __float_as_uint(f);
  uint32_t r = u + 0x7fffu + ((u >> 16) & 1u); // RNE
  return (short)(r >> 16);
}

// monotonic float<->uint map for deterministic atomicMax (0 = minimum)
static __device__ __forceinline__ unsigned int flipf(float v) {
  unsigned int u = __float_as_uint(v);
  return (u & 0x80000000u) ? ~u : (u | 0x80000000u);
}
static __device__ __forceinline__ float unflipf(unsigned int u) {
  return __uint_as_float((u & 0x80000000u) ? (u & 0x7fffffffu) : ~u);
}

// pad-mask accessor robust to bool-ABI (byteFlag=1: 1B/elem, 0: int32/elem)
static __device__ __forceinline__ bool is_pad(const void* pad, int byteFlag, int j) {
  return byteFlag ? (((const unsigned char*)pad)[j] != 0)
                  : (((const int*)pad)[j] != 0);
}

// ---------------- detect bool ABI + zero gmax ----------------
__global__ __launch_bounds__(256) void k_detect(const unsigned int* __restrict__ pad_raw,
                                                int* __restrict__ flag,
                                                unsigned int* __restrict__ gmax) {
  if (threadIdx.x < 128) gmax[threadIdx.x] = 0u;
  int any_gt1 = 0;
  for (int i = threadIdx.x; i < 16384; i += 256)
    if (pad_raw[i] > 1u) any_gt1 = 1;
  unsigned long long m = __ballot(any_gt1);
  __shared__ int s[4];
  if ((threadIdx.x & 63) == 0) s[threadIdx.x >> 6] = (m != 0ull) ? 1 : 0;
  __syncthreads();
  if (threadIdx.x == 0) flag[0] = (s[0] | s[1] | s[2] | s[3]);
}

// ---------------- k0: repack W1 [512][128] fp32 -> MFMA B-fragment order bf16 ----------------
// wfrag[(c*8 + t)*64 + lane][i] = bf16( W1[c*32 + (lane>>4)*8 + i][t*16 + (lane&15)] )
__global__ void k0_wfrag(const float* __restrict__ W1, short* __restrict__ wfrag) {
  int tid = blockIdx.x * blockDim.x + threadIdx.x;
  if (tid >= 16 * 8 * 64) return;
  int l = tid & 63;
  int t = (tid >> 6) & 7;
  int c = tid >> 9;
  int kbase = c * 32 + (l >> 4) * 8;
  int col = t * 16 + (l & 15);
  bf16x8 frag;
#pragma unroll
  for (int i = 0; i < 8; ++i) frag[i] = f2bf(W1[(size_t)(kbase + i) * DDIM + col]);
  ((bf16x8*)wfrag)[tid] = frag;
}

// ---------------- k1: scores + deterministic atomicMax of per-(b,q) max ----------------
// block=256 (4 waves) -> 128 rows; wave owns 32 rows (2 row-tiles).
// B chunk (8KB) double-buffered in LDS via global_load_lds; x prefetched 1 chunk ahead.
__global__ __launch_bounds__(256, 2) void k1_scores(const float* __restrict__ x,
                                                    const short* __restrict__ wfrag,
                                                    const float* __restrict__ W2,
                                                    const int* __restrict__ ids,
                                                    const void* __restrict__ pad,
                                                    const int* __restrict__ flag,
                                                    float* __restrict__ A,
                                                    unsigned int* __restrict__ gmax) {
  __shared__ short ldsb[2][4096]; // 2 x 8KB chunk buffers
  const int tid = threadIdx.x, wave = tid >> 6, lane = tid & 63;
  const int rowBase = blockIdx.x * 128 + wave * 32;
  const float* xp = x + (size_t)(rowBase + (lane & 15)) * LDIM + ((lane >> 4) * 8);

  f32x4 acc[2][8];
#pragma unroll
  for (int rt = 0; rt < 2; ++rt)
#pragma unroll
    for (int t = 0; t < 8; ++t) acc[rt][t] = (f32x4){0.f, 0.f, 0.f, 0.f};

#define STAGE(c, buf)                                                                   \
  {                                                                                     \
    const unsigned int* src_ = (const unsigned int*)(wfrag + (size_t)(c) * 4096);       \
    __builtin_amdgcn_global_load_lds(                                                   \
        (const __attribute__((address_space(1))) unsigned int*)(src_ + tid * 4),        \
        (__attribute__((address_space(3))) unsigned int*)&ldsb[buf][wave << 9],         \
        16, 0, 0);                                                                      \
    __builtin_amdgcn_global_load_lds(                                                   \
        (const __attribute__((address_space(1))) unsigned int*)(src_ + 1024 + tid * 4), \
        (__attribute__((address_space(3))) unsigned int*)&ldsb[buf][2048 + (wave << 9)],\
        16, 0, 0);                                                                      \
  }

#define ALOAD(c)                                                   \
  {                                                                \
    av00 = *(const float4*)(xp + (c) * 32);                        \
    av01 = *(const float4*)(xp + (c) * 32 + 4);                    \
    av10 = *(const float4*)(xp + 16 * LDIM + (c) * 32);            \
    av11 = *(const float4*)(xp + 16 * LDIM + (c) * 32 + 4);        \
  }

  float4 av00, av01, av10, av11;
  STAGE(0, 0);
  ALOAD(0);

  for (int c = 0; c < 16; ++c) {
    const int buf = c & 1;
    __syncthreads(); // compiler drains vmcnt -> stage(c) and aload(c) landed
    if (c < 15) STAGE(c + 1, buf ^ 1);
    bf16x8 af0, af1;
    af0[0] = f2bf(av00.x); af0[1] = f2bf(av00.y); af0[2] = f2bf(av00.z); af0[3] = f2bf(av00.w);
    af0[4] = f2bf(av01.x); af0[5] = f2bf(av01.y); af0[6] = f2bf(av01.z); af0[7] = f2bf(av01.w);
    af1[0] = f2bf(av10.x); af1[1] = f2bf(av10.y); af1[2] = f2bf(av10.z); af1[3] = f2bf(av10.w);
    af1[4] = f2bf(av11.x); af1[5] = f2bf(av11.y); af1[6] = f2bf(av11.z); af1[7] = f2bf(av11.w);
    if (c < 15) ALOAD(c + 1); // prefetch next chunk's x across the next barrier
#pragma unroll
    for (int t = 0; t < 8; ++t) {
      bf16x8 bfr = *(const bf16x8*)&ldsb[buf][t * 512 + lane * 8];
      acc[0][t] = __builtin_amdgcn_mfma_f32_16x16x32_bf16(af0, bfr, acc[0][t], 0, 0, 0);
      acc[1][t] = __builtin_amdgcn_mfma_f32_16x16x32_bf16(af1, bfr, acc[1][t], 0, 0, 0);
    }
  }
#undef STAGE
#undef ALOAD

  // epilogue: tanh + dot W2 + 16-lane reduce; D layout col=lane&15(+16t), row=(lane>>4)*4+r
  float w2v[8];
#pragma unroll
  for (int t = 0; t < 8; ++t) w2v[t] = W2[t * 16 + (lane & 15)];
  const int bfl = flag[0];
#pragma unroll
  for (int rt = 0; rt < 2; ++rt) {
    float asum[4] = {0.f, 0.f, 0.f, 0.f};
#pragma unroll
    for (int t = 0; t < 8; ++t) {
#pragma unroll
      for (int r = 0; r < 4; ++r) {
        float h = 1.f - 2.f / (__expf(2.f * acc[rt][t][r]) + 1.f); // tanh
        asum[r] += h * w2v[t];
      }
    }
#pragma unroll
    for (int m = 1; m < 16; m <<= 1) {
#pragma unroll
      for (int r = 0; r < 4; ++r) asum[r] += __shfl_xor(asum[r], m, 64);
    }
    if ((lane & 15) == 0) {
      int rb = rowBase + rt * 16 + (lane >> 4) * 4;
#pragma unroll
      for (int r = 0; r < 4; ++r) {
        int row = rb + r;
        float v = asum[r];
        A[row] = v;
        if (!is_pad(pad, bfl, row)) {
          int q = ids[row];
          int b = row >> 13;
          atomicMax(&gmax[(b << 4) + q], flipf(v));
        }
      }
    }
  }
}

// ---------------- k3: unnormalized weighted pooling partials + weight sums ----------------
__global__ __launch_bounds__(256) void k3_pool(const float* __restrict__ x,
                                               const float* __restrict__ A,
                                               const int* __restrict__ ids,
                                               const void* __restrict__ pad,
                                               const int* __restrict__ flag,
                                               const unsigned int* __restrict__ gmax,
                                               float* __restrict__ partial,
                                               float* __restrict__ wsum) {
  int blk = blockIdx.x;
  int s = blk & 7, q = (blk >> 3) & 15, b = blk >> 7;
  int wave = threadIdx.x >> 6, lane = threadIdx.x & 63;
  int bfl = flag[0];
  __shared__ float w_lds[1024];
  __shared__ unsigned short j_lds[1024];
  __shared__ int cnt[4];
  __shared__ float wred[4];

  unsigned int mraw = gmax[(b << 4) + q];
  float mx = (mraw == 0u) ? 0.f : unflipf(mraw);
  const int base = b * NTOK;

  int wbase = wave * 256;
  int wpos = wbase;
  float wacc = 0.f;
#pragma unroll
  for (int g = 0; g < 4; ++g) {
    int j = s * SEGLEN + wave * 256 + g * 64 + lane;
    bool mem = (ids[base + j] == q) && !is_pad(pad, bfl, base + j);
    float wt = mem ? __expf(A[base + j] - mx) : 0.f;
    wacc += wt;
    unsigned long long mask = __ballot(mem);
    if (mem) {
      int pos = wpos + __popcll(mask & ((1ull << lane) - 1ull));
      w_lds[pos] = wt;
      j_lds[pos] = (unsigned short)j;
    }
    wpos += __popcll(mask);
  }
#pragma unroll
  for (int m = 1; m < 64; m <<= 1) wacc += __shfl_xor(wacc, m, 64);
  if (lane == 0) { cnt[wave] = wpos - wbase; wred[wave] = wacc; }
  __syncthreads();

  int c0 = threadIdx.x * 2;
  float ax = 0.f, ay = 0.f;
  for (int w = 0; w < 4; ++w) {
    int nw = cnt[w];
#pragma unroll 2
    for (int e = 0; e < nw; ++e) {
      float wt = w_lds[w * 256 + e];
      int j = j_lds[w * 256 + e];
      const float* xr = x + (size_t)(base + j) * LDIM + c0;
      ax += wt * xr[0];
      ay += wt * xr[1];
    }
  }
  size_t po = (size_t)blk * LDIM + c0; // partial[b][q][s][c]
  partial[po] = ax;
  partial[po + 1] = ay;
  if (threadIdx.x == 0) wsum[blk] = wred[0] + wred[1] + wred[2] + wred[3];
}

// ---------------- k4: combine partials over segments, normalize ----------------
__global__ void k4_reduce(const float* __restrict__ partial, const float* __restrict__ wsum,
                          float* __restrict__ out) {
  int e = blockIdx.x * blockDim.x + threadIdx.x;
  if (e >= BATCH * NQ * LDIM) return;
  int bi = e >> 9, c = e & 511;
  float ps = 0.f, ws = 0.f;
#pragma unroll
  for (int t = 0; t < 8; ++t) {
    ps += partial[(size_t)(bi * 8 + t) * LDIM + c];
    ws += wsum[bi * 8 + t];
  }
  out[e] = (ws > 0.f) ? (ps / ws) : 0.f;
}

extern "C" void kernel_launch(void* const* d_in, const int* in_sizes, int n_in,
                              void* d_out, int out_size, void* d_ws, size_t ws_size,
                              hipStream_t stream) {
  const float* x = (const float*)d_in[0];
  const float* W1 = (const float*)d_in[1];
  const float* W2 = (const float*)d_in[2];
  const int* ids = (const int*)d_in[3];
  const void* pad = d_in[4]; // bool ABI detected at runtime
  float* out = (float*)d_out;

  char* ws = (char*)d_ws;
  short* wfrag = (short*)ws;                        // 131072 B
  float* A = (float*)(ws + 131072);                 // 262144 B
  unsigned int* gmax = (unsigned int*)(ws + 393216);// 512 B
  float* wsum = (float*)(ws + 393728);              // 4096 B
  int* flag = (int*)(ws + 397824);                  // 4 B (pad to 397952)
  float* partial = (float*)(ws + 397952);           // 2097152 B

  hipLaunchKernelGGL(k_detect, dim3(1), dim3(256), 0, stream, (const unsigned int*)pad, flag, gmax);
  hipLaunchKernelGGL(k0_wfrag, dim3(32), dim3(256), 0, stream, W1, wfrag);
  hipLaunchKernelGGL(k1_scores, dim3((BATCH * NTOK) / 128), dim3(256), 0, stream,
                     x, wfrag, W2, ids, pad, flag, A, gmax);
  hipLaunchKernelGGL(k3_pool, dim3(BATCH * NQ * NSEG), dim3(256), 0, stream,
                     x, A, ids, pad, flag, gmax, partial, wsum);
  hipLaunchKernelGGL(k4_reduce, dim3((BATCH * NQ * LDIM) / 256), dim3(256), 0, stream,
                     partial, wsum, out);
}

// Round 4
// 71.634 us; speedup vs baseline: 1.8007x; 1.6361x over previous
//
#include <hip/hip_runtime.h>
#include <hip/hip_bf16.h>
#include <cstdint>
#include <cstddef>

typedef __attribute__((ext_vector_type(8))) short bf16x8;
typedef __attribute__((ext_vector_type(4))) float f32x4;

#define BATCH 8
#define NTOK 8192
#define LDIM 512
#define DDIM 128
#define NQ 16
#define NSEG 8
#define SEGLEN (NTOK / NSEG) /* 1024 */

static __device__ __forceinline__ short f2bf(float f) {
  uint32_t u = __float_as_uint(f);
  uint32_t r = u + 0x7fffu + ((u >> 16) & 1u); // RNE
  return (short)(r >> 16);
}

static __device__ __forceinline__ bf16x8 cvt8(float4 a, float4 b) {
  bf16x8 o;
  o[0] = f2bf(a.x); o[1] = f2bf(a.y); o[2] = f2bf(a.z); o[3] = f2bf(a.w);
  o[4] = f2bf(b.x); o[5] = f2bf(b.y); o[6] = f2bf(b.z); o[7] = f2bf(b.w);
  return o;
}

// monotonic float<->uint map for deterministic atomicMax (0 = minimum)
static __device__ __forceinline__ unsigned int flipf(float v) {
  unsigned int u = __float_as_uint(v);
  return (u & 0x80000000u) ? ~u : (u | 0x80000000u);
}
static __device__ __forceinline__ float unflipf(unsigned int u) {
  return __uint_as_float((u & 0x80000000u) ? (u & 0x7fffffffu) : ~u);
}

// pad-mask accessor robust to bool-ABI (byteFlag=1: 1B/elem, 0: int32/elem)
static __device__ __forceinline__ bool is_pad(const void* pad, int byteFlag, int j) {
  return byteFlag ? (((const unsigned char*)pad)[j] != 0)
                  : (((const int*)pad)[j] != 0);
}

// ---------------- detect bool ABI + zero gmax ----------------
__global__ __launch_bounds__(256) void k_detect(const unsigned int* __restrict__ pad_raw,
                                                int* __restrict__ flag,
                                                unsigned int* __restrict__ gmax) {
  if (threadIdx.x < 128) gmax[threadIdx.x] = 0u;
  int any_gt1 = 0;
  for (int i = threadIdx.x; i < 16384; i += 256)
    if (pad_raw[i] > 1u) any_gt1 = 1;
  unsigned long long m = __ballot(any_gt1);
  __shared__ int s[4];
  if ((threadIdx.x & 63) == 0) s[threadIdx.x >> 6] = (m != 0ull) ? 1 : 0;
  __syncthreads();
  if (threadIdx.x == 0) flag[0] = (s[0] | s[1] | s[2] | s[3]);
}

// ---------------- k0: repack W1 [512][128] fp32 -> MFMA B-fragment order bf16 ----------------
// wfrag[(c*8 + t)*64 + lane][i] = bf16( W1[c*32 + (lane>>4)*8 + i][t*16 + (lane&15)] )
__global__ void k0_wfrag(const float* __restrict__ W1, short* __restrict__ wfrag) {
  int tid = blockIdx.x * blockDim.x + threadIdx.x;
  if (tid >= 16 * 8 * 64) return;
  int l = tid & 63;
  int t = (tid >> 6) & 7;
  int c = tid >> 9;
  int kbase = c * 32 + (l >> 4) * 8;
  int col = t * 16 + (l & 15);
  bf16x8 frag;
#pragma unroll
  for (int i = 0; i < 8; ++i) frag[i] = f2bf(W1[(size_t)(kbase + i) * DDIM + col]);
  ((bf16x8*)wfrag)[tid] = frag;
}

// ---------------- k1: scores; W1 staged in LDS once (2 halves), no steady-state barriers ----
// 512 thr (8 waves) x 16 rows/wave = 128 rows/block; grid 512 (2 blocks/CU).
__global__ __launch_bounds__(512, 4) void k1_scores(const float* __restrict__ x,
                                                    const short* __restrict__ wfrag,
                                                    const float* __restrict__ W2,
                                                    const int* __restrict__ ids,
                                                    const void* __restrict__ pad,
                                                    const int* __restrict__ flag,
                                                    float* __restrict__ A,
                                                    unsigned int* __restrict__ gmax) {
  __shared__ short ldsw[32768]; // 64 KB: one half of wfrag (K-chunks 0-7 or 8-15)
  __shared__ unsigned int qmax[16];
  const int tid = threadIdx.x, wave = tid >> 6, lane = tid & 63;
  const int rowBase = blockIdx.x * 128 + wave * 16;
  const int b = rowBase >> 13;
  const float* xp = x + (size_t)(rowBase + (lane & 15)) * LDIM + ((lane >> 4) * 8);
  if (tid < 16) qmax[tid] = 0u;

// stage 64KB half h of wfrag into LDS (512 thr x 8 x 16B), linear dest
#define STAGE(h)                                                                              \
  {                                                                                           \
    const unsigned int* src_ = (const unsigned int*)wfrag + (h) * 16384;                      \
    _Pragma("unroll")                                                                         \
    for (int i = 0; i < 8; ++i) {                                                             \
      __builtin_amdgcn_global_load_lds(                                                       \
          (const __attribute__((address_space(1))) unsigned int*)(src_ + (i * 512 + tid) * 4),\
          (__attribute__((address_space(3))) unsigned int*)&ldsw[(i * 512 + wave * 64) * 8],  \
          16, 0, 0);                                                                          \
    }                                                                                         \
  }

#define ALOAD(dst, c)                                  \
  {                                                    \
    dst[0] = *(const float4*)(xp + (c) * 32);          \
    dst[1] = *(const float4*)(xp + (c) * 32 + 4);      \
  }

  f32x4 acc[8];
#pragma unroll
  for (int t = 0; t < 8; ++t) acc[t] = (f32x4){0.f, 0.f, 0.f, 0.f};
  float4 avbuf[2][2];

  STAGE(0);
  ALOAD(avbuf[0], 0);
  ALOAD(avbuf[1], 1);
  __syncthreads(); // stage-0 + first x loads landed

  // ---- half 0: chunks 0..7, no barriers, x prefetched 2 deep ----
#pragma unroll
  for (int cc = 0; cc < 8; ++cc) {
    bf16x8 af = cvt8(avbuf[cc & 1][0], avbuf[cc & 1][1]);
    if (cc < 6) ALOAD(avbuf[cc & 1], cc + 2);
#pragma unroll
    for (int t = 0; t < 8; ++t) {
      bf16x8 bfr = *(const bf16x8*)&ldsw[((cc * 8 + t) * 64 + lane) * 8];
      acc[t] = __builtin_amdgcn_mfma_f32_16x16x32_bf16(af, bfr, acc[t], 0, 0, 0);
    }
  }
  ALOAD(avbuf[0], 8);
  ALOAD(avbuf[1], 9);
  __syncthreads(); // all waves done reading half-0 LDS
  STAGE(1);
  __syncthreads(); // stage-1 landed

  // ---- half 1: chunks 8..15 ----
#pragma unroll
  for (int cc = 0; cc < 8; ++cc) {
    bf16x8 af = cvt8(avbuf[cc & 1][0], avbuf[cc & 1][1]);
    if (cc < 6) ALOAD(avbuf[cc & 1], 10 + cc);
#pragma unroll
    for (int t = 0; t < 8; ++t) {
      bf16x8 bfr = *(const bf16x8*)&ldsw[((cc * 8 + t) * 64 + lane) * 8];
      acc[t] = __builtin_amdgcn_mfma_f32_16x16x32_bf16(af, bfr, acc[t], 0, 0, 0);
    }
  }
#undef STAGE
#undef ALOAD

  // epilogue: tanh + dot W2 + 16-lane reduce; D layout col=lane&15(+16t), row=(lane>>4)*4+r
  float w2v[8];
#pragma unroll
  for (int t = 0; t < 8; ++t) w2v[t] = W2[t * 16 + (lane & 15)];
  const int bfl = flag[0];
  float asum[4] = {0.f, 0.f, 0.f, 0.f};
#pragma unroll
  for (int t = 0; t < 8; ++t) {
#pragma unroll
    for (int r = 0; r < 4; ++r) {
      float h = 1.f - 2.f / (__expf(2.f * acc[t][r]) + 1.f); // tanh
      asum[r] += h * w2v[t];
    }
  }
#pragma unroll
  for (int m = 1; m < 16; m <<= 1) {
#pragma unroll
    for (int r = 0; r < 4; ++r) asum[r] += __shfl_xor(asum[r], m, 64);
  }
  if ((lane & 15) == 0) {
    int rb = rowBase + (lane >> 4) * 4;
#pragma unroll
    for (int r = 0; r < 4; ++r) {
      int row = rb + r;
      float v = asum[r];
      A[row] = v;
      if (!is_pad(pad, bfl, row)) atomicMax(&qmax[ids[row]], flipf(v));
    }
  }
  __syncthreads();
  if (tid < 16 && qmax[tid] != 0u) atomicMax(&gmax[(b << 4) + tid], qmax[tid]);
}

// ---------------- k3: unnormalized weighted pooling partials + weight sums ----------------
__global__ __launch_bounds__(256) void k3_pool(const float* __restrict__ x,
                                               const float* __restrict__ A,
                                               const int* __restrict__ ids,
                                               const void* __restrict__ pad,
                                               const int* __restrict__ flag,
                                               const unsigned int* __restrict__ gmax,
                                               float* __restrict__ partial,
                                               float* __restrict__ wsum) {
  int blk = blockIdx.x;
  int s = blk & 7, q = (blk >> 3) & 15, b = blk >> 7;
  int wave = threadIdx.x >> 6, lane = threadIdx.x & 63;
  int bfl = flag[0];
  __shared__ float w_lds[1024];
  __shared__ unsigned short j_lds[1024];
  __shared__ int cnt[4];
  __shared__ float wred[4];

  unsigned int mraw = gmax[(b << 4) + q];
  float mx = (mraw == 0u) ? 0.f : unflipf(mraw);
  const int base = b * NTOK;

  int wbase = wave * 256;
  int wpos = wbase;
  float wacc = 0.f;
#pragma unroll
  for (int g = 0; g < 4; ++g) {
    int j = s * SEGLEN + wave * 256 + g * 64 + lane;
    bool mem = (ids[base + j] == q) && !is_pad(pad, bfl, base + j);
    float wt = mem ? __expf(A[base + j] - mx) : 0.f;
    wacc += wt;
    unsigned long long mask = __ballot(mem);
    if (mem) {
      int pos = wpos + __popcll(mask & ((1ull << lane) - 1ull));
      w_lds[pos] = wt;
      j_lds[pos] = (unsigned short)j;
    }
    wpos += __popcll(mask);
  }
#pragma unroll
  for (int m = 1; m < 64; m <<= 1) wacc += __shfl_xor(wacc, m, 64);
  if (lane == 0) { cnt[wave] = wpos - wbase; wred[wave] = wacc; }
  __syncthreads();

  int c0 = threadIdx.x * 2;
  float ax = 0.f, ay = 0.f;
  for (int w = 0; w < 4; ++w) {
    int nw = cnt[w];
#pragma unroll 2
    for (int e = 0; e < nw; ++e) {
      float wt = w_lds[w * 256 + e];
      int j = j_lds[w * 256 + e];
      const float* xr = x + (size_t)(base + j) * LDIM + c0;
      ax += wt * xr[0];
      ay += wt * xr[1];
    }
  }
  size_t po = (size_t)blk * LDIM + c0; // partial[b][q][s][c]
  partial[po] = ax;
  partial[po + 1] = ay;
  if (threadIdx.x == 0) wsum[blk] = wred[0] + wred[1] + wred[2] + wred[3];
}

// ---------------- k4: combine partials over segments, normalize ----------------
__global__ void k4_reduce(const float* __restrict__ partial, const float* __restrict__ wsum,
                          float* __restrict__ out) {
  int e = blockIdx.x * blockDim.x + threadIdx.x;
  if (e >= BATCH * NQ * LDIM) return;
  int bi = e >> 9, c = e & 511;
  float ps = 0.f, ws = 0.f;
#pragma unroll
  for (int t = 0; t < 8; ++t) {
    ps += partial[(size_t)(bi * 8 + t) * LDIM + c];
    ws += wsum[bi * 8 + t];
  }
  out[e] = (ws > 0.f) ? (ps / ws) : 0.f;
}

extern "C" void kernel_launch(void* const* d_in, const int* in_sizes, int n_in,
                              void* d_out, int out_size, void* d_ws, size_t ws_size,
                              hipStream_t stream) {
  const float* x = (const float*)d_in[0];
  const float* W1 = (const float*)d_in[1];
  const float* W2 = (const float*)d_in[2];
  const int* ids = (const int*)d_in[3];
  const void* pad = d_in[4]; // bool ABI detected at runtime
  float* out = (float*)d_out;

  char* ws = (char*)d_ws;
  short* wfrag = (short*)ws;                        // 131072 B
  float* A = (float*)(ws + 131072);                 // 262144 B
  unsigned int* gmax = (unsigned int*)(ws + 393216);// 512 B
  float* wsum = (float*)(ws + 393728);              // 4096 B
  int* flag = (int*)(ws + 397824);                  // 4 B (pad to 397952)
  float* partial = (float*)(ws + 397952);           // 2097152 B

  hipLaunchKernelGGL(k_detect, dim3(1), dim3(256), 0, stream, (const unsigned int*)pad, flag, gmax);
  hipLaunchKernelGGL(k0_wfrag, dim3(32), dim3(256), 0, stream, W1, wfrag);
  hipLaunchKernelGGL(k1_scores, dim3((BATCH * NTOK) / 128), dim3(512), 0, stream,
                     x, wfrag, W2, ids, pad, flag, A, gmax);
  hipLaunchKernelGGL(k3_pool, dim3(BATCH * NQ * NSEG), dim3(256), 0, stream,
                     x, A, ids, pad, flag, gmax, partial, wsum);
  hipLaunchKernelGGL(k4_reduce, dim3((BATCH * NQ * LDIM) / 256), dim3(256), 0, stream,
                     partial, wsum, out);
}

// Round 5
// 70.673 us; speedup vs baseline: 1.8252x; 1.0136x over previous
//
#include <hip/hip_runtime.h>
#include <hip/hip_bf16.h>
#include <cstdint>
#include <cstddef>

typedef __attribute__((ext_vector_type(8))) short bf16x8;
typedef __attribute__((ext_vector_type(4))) float f32x4;

#define BATCH 8
#define NTOK 8192
#define LDIM 512
#define DDIM 128
#define NQ 16
#define NSEG 8
#define SEGLEN (NTOK / NSEG) /* 1024 */

static __device__ __forceinline__ short f2bf(float f) {
  uint32_t u = __float_as_uint(f);
  uint32_t r = u + 0x7fffu + ((u >> 16) & 1u); // RNE
  return (short)(r >> 16);
}

static __device__ __forceinline__ bf16x8 cvt8(float4 a, float4 b) {
  bf16x8 o;
  o[0] = f2bf(a.x); o[1] = f2bf(a.y); o[2] = f2bf(a.z); o[3] = f2bf(a.w);
  o[4] = f2bf(b.x); o[5] = f2bf(b.y); o[6] = f2bf(b.z); o[7] = f2bf(b.w);
  return o;
}

// monotonic float<->uint map for deterministic atomicMax (0 = minimum)
static __device__ __forceinline__ unsigned int flipf(float v) {
  unsigned int u = __float_as_uint(v);
  return (u & 0x80000000u) ? ~u : (u | 0x80000000u);
}
static __device__ __forceinline__ float unflipf(unsigned int u) {
  return __uint_as_float((u & 0x80000000u) ? (u & 0x7fffffffu) : ~u);
}

// pad-mask accessor robust to bool-ABI (byteFlag=1: 1B/elem, 0: int32/elem)
static __device__ __forceinline__ bool is_pad(const void* pad, int byteFlag, int j) {
  return byteFlag ? (((const unsigned char*)pad)[j] != 0)
                  : (((const int*)pad)[j] != 0);
}

// ---------------- k0: repack W1 -> MFMA B-frag order bf16; block 0 also: detect ABI + zero gmax
// wfrag[(c*8 + t)*64 + lane][i] = bf16( W1[c*32 + (lane>>4)*8 + i][t*16 + (lane&15)] )
__global__ __launch_bounds__(256) void k0_wfrag(const float* __restrict__ W1,
                                                short* __restrict__ wfrag,
                                                const unsigned int* __restrict__ pad_raw,
                                                int* __restrict__ flag,
                                                unsigned int* __restrict__ gmax) {
  int tid = blockIdx.x * blockDim.x + threadIdx.x;
  if (tid < 16 * 8 * 64) {
    int l = tid & 63;
    int t = (tid >> 6) & 7;
    int c = tid >> 9;
    int kbase = c * 32 + (l >> 4) * 8;
    int col = t * 16 + (l & 15);
    bf16x8 frag;
#pragma unroll
    for (int i = 0; i < 8; ++i) frag[i] = f2bf(W1[(size_t)(kbase + i) * DDIM + col]);
    ((bf16x8*)wfrag)[tid] = frag;
  }
  if (blockIdx.x == 0) {
    if (threadIdx.x < 128) gmax[threadIdx.x] = 0u;
    int any_gt1 = 0;
    for (int i = threadIdx.x; i < 16384; i += 256)
      if (pad_raw[i] > 1u) any_gt1 = 1;
    unsigned long long m = __ballot(any_gt1);
    __shared__ int s[4];
    if ((threadIdx.x & 63) == 0) s[threadIdx.x >> 6] = (m != 0ull) ? 1 : 0;
    __syncthreads();
    if (threadIdx.x == 0) flag[0] = (s[0] | s[1] | s[2] | s[3]);
  }
}

// ---------------- k1: scores; W1 staged in LDS in 4x32KB quarters (4 blocks/CU) ----------------
// 512 thr (8 waves) x 16 rows/wave = 128 rows/block; grid 512.
__global__ __launch_bounds__(512, 6) void k1_scores(const float* __restrict__ x,
                                                    const short* __restrict__ wfrag,
                                                    const float* __restrict__ W2,
                                                    const int* __restrict__ ids,
                                                    const void* __restrict__ pad,
                                                    const int* __restrict__ flag,
                                                    float* __restrict__ A,
                                                    unsigned int* __restrict__ gmax) {
  __shared__ short ldsw[16384]; // 32 KB: one quarter of wfrag (4 K-chunks)
  __shared__ unsigned int qmax[16];
  const int tid = threadIdx.x, wave = tid >> 6, lane = tid & 63;
  const int rowBase = blockIdx.x * 128 + wave * 16;
  const int b = rowBase >> 13;
  const float* xp = x + (size_t)(rowBase + (lane & 15)) * LDIM + ((lane >> 4) * 8);
  if (tid < 16) qmax[tid] = 0u;

// stage 32KB quarter qd of wfrag into LDS (512 thr x 4 x 16B), linear dest
#define STAGE(qd)                                                                             \
  {                                                                                           \
    const unsigned int* src_ = (const unsigned int*)wfrag + (qd) * 8192;                      \
    _Pragma("unroll")                                                                         \
    for (int i = 0; i < 4; ++i) {                                                             \
      __builtin_amdgcn_global_load_lds(                                                       \
          (const __attribute__((address_space(1))) unsigned int*)(src_ + (i * 512 + tid) * 4),\
          (__attribute__((address_space(3))) unsigned int*)&ldsw[(i * 512 + wave * 64) * 8],  \
          16, 0, 0);                                                                          \
    }                                                                                         \
  }

#define ALOAD(dst, c)                                  \
  {                                                    \
    dst[0] = *(const float4*)(xp + (c) * 32);          \
    dst[1] = *(const float4*)(xp + (c) * 32 + 4);      \
  }

  f32x4 acc[8];
#pragma unroll
  for (int t = 0; t < 8; ++t) acc[t] = (f32x4){0.f, 0.f, 0.f, 0.f};
  float4 avbuf[2][2];

  STAGE(0);
  ALOAD(avbuf[0], 0);
  ALOAD(avbuf[1], 1);
  __syncthreads(); // stage-0 + first x loads landed

#pragma unroll
  for (int qd = 0; qd < 4; ++qd) {
#pragma unroll
    for (int cc = 0; cc < 4; ++cc) {
      const int c = qd * 4 + cc;
      bf16x8 af = cvt8(avbuf[c & 1][0], avbuf[c & 1][1]);
      if (c < 14) ALOAD(avbuf[c & 1], c + 2); // keep 2 chunks of x in flight
#pragma unroll
      for (int t = 0; t < 8; ++t) {
        bf16x8 bfr = *(const bf16x8*)&ldsw[((cc * 8 + t) * 64 + lane) * 8];
        acc[t] = __builtin_amdgcn_mfma_f32_16x16x32_bf16(af, bfr, acc[t], 0, 0, 0);
      }
    }
    if (qd < 3) {
      __syncthreads(); // all waves done reading quarter qd
      STAGE(qd + 1);
      __syncthreads(); // quarter qd+1 landed
    }
  }
#undef STAGE
#undef ALOAD

  // epilogue: tanh + dot W2 + 16-lane reduce; D layout col=lane&15(+16t), row=(lane>>4)*4+r
  float w2v[8];
#pragma unroll
  for (int t = 0; t < 8; ++t) w2v[t] = W2[t * 16 + (lane & 15)];
  const int bfl = flag[0];
  float asum[4] = {0.f, 0.f, 0.f, 0.f};
#pragma unroll
  for (int t = 0; t < 8; ++t) {
#pragma unroll
    for (int r = 0; r < 4; ++r) {
      float h = 1.f - 2.f / (__expf(2.f * acc[t][r]) + 1.f); // tanh
      asum[r] += h * w2v[t];
    }
  }
#pragma unroll
  for (int m = 1; m < 16; m <<= 1) {
#pragma unroll
    for (int r = 0; r < 4; ++r) asum[r] += __shfl_xor(asum[r], m, 64);
  }
  if ((lane & 15) == 0) {
    int rb = rowBase + (lane >> 4) * 4;
#pragma unroll
    for (int r = 0; r < 4; ++r) {
      int row = rb + r;
      float v = asum[r];
      A[row] = v;
      if (!is_pad(pad, bfl, row)) atomicMax(&qmax[ids[row]], flipf(v));
    }
  }
  __syncthreads();
  if (tid < 16 && qmax[tid] != 0u) atomicMax(&gmax[(b << 4) + tid], qmax[tid]);
}

// ---------------- k3: pooling partials; unified compaction + float4 x reads ----------------
// grid ((b*16+q)*8+s); 2 row-groups x 128 col-threads (float4 = 512 cols).
__global__ __launch_bounds__(256) void k3_pool(const float* __restrict__ x,
                                               const float* __restrict__ A,
                                               const int* __restrict__ ids,
                                               const void* __restrict__ pad,
                                               const int* __restrict__ flag,
                                               const unsigned int* __restrict__ gmax,
                                               float* __restrict__ partial,
                                               float* __restrict__ wsum) {
  int blk = blockIdx.x;
  int s = blk & 7, q = (blk >> 3) & 15, b = blk >> 7;
  int wave = threadIdx.x >> 6, lane = threadIdx.x & 63;
  int bfl = flag[0];
  __shared__ float w_u[1024];
  __shared__ unsigned short j_u[1024];
  __shared__ int cnt[4];
  __shared__ float wred[4];

  unsigned int mraw = gmax[(b << 4) + q];
  float mx = (mraw == 0u) ? 0.f : unflipf(mraw);
  const int base = b * NTOK;
  const int tokBase = s * SEGLEN + wave * 256;

  // pass 1: per-wave member counts
  int myCnt = 0;
#pragma unroll
  for (int g = 0; g < 4; ++g) {
    int j = tokBase + g * 64 + lane;
    bool mem = (ids[base + j] == q) && !is_pad(pad, bfl, base + j);
    myCnt += __popcll(__ballot(mem));
  }
  if (lane == 0) cnt[wave] = myCnt;
  __syncthreads();

  // prefix offset for this wave
  int wpos = 0;
#pragma unroll
  for (int w = 0; w < 4; ++w) if (w < wave) wpos += cnt[w];
  const int total = cnt[0] + cnt[1] + cnt[2] + cnt[3];

  // pass 2: compact (token idx, unnormalized weight) into unified list
  float wacc = 0.f;
#pragma unroll
  for (int g = 0; g < 4; ++g) {
    int j = tokBase + g * 64 + lane;
    bool mem = (ids[base + j] == q) && !is_pad(pad, bfl, base + j);
    float wt = mem ? __expf(A[base + j] - mx) : 0.f;
    wacc += wt;
    unsigned long long mask = __ballot(mem);
    if (mem) {
      int pos = wpos + __popcll(mask & ((1ull << lane) - 1ull));
      w_u[pos] = wt;
      j_u[pos] = (unsigned short)j;
    }
    wpos += __popcll(mask);
  }
#pragma unroll
  for (int m = 1; m < 64; m <<= 1) wacc += __shfl_xor(wacc, m, 64);
  if (lane == 0) wred[wave] = wacc;
  __syncthreads();

  // accumulate: group grp handles entries [e0,e1), 128 threads x float4 cols
  int grp = threadIdx.x >> 7, ct = threadIdx.x & 127;
  int c0 = ct * 4;
  int half = (total + 1) >> 1;
  int e0 = grp ? half : 0;
  int e1 = grp ? total : half;
  float4 av = {0.f, 0.f, 0.f, 0.f};
  for (int e = e0; e < e1; ++e) {
    float wt = w_u[e];
    int j = j_u[e];
    float4 xr = *(const float4*)(x + (size_t)(base + j) * LDIM + c0);
    av.x += wt * xr.x; av.y += wt * xr.y; av.z += wt * xr.z; av.w += wt * xr.w;
  }
  // partial slot = blk*2 + grp
  *(float4*)(partial + ((size_t)(blk * 2 + grp)) * LDIM + c0) = av;
  if (threadIdx.x == 0) wsum[blk] = wred[0] + wred[1] + wred[2] + wred[3];
}

// ---------------- k4: combine partials (16 slots) + normalize ----------------
__global__ void k4_reduce(const float* __restrict__ partial, const float* __restrict__ wsum,
                          float* __restrict__ out) {
  int e = blockIdx.x * blockDim.x + threadIdx.x;
  if (e >= BATCH * NQ * LDIM) return;
  int bi = e >> 9, c = e & 511;
  float ps = 0.f, ws = 0.f;
#pragma unroll
  for (int t = 0; t < 16; ++t) ps += partial[(size_t)(bi * 16 + t) * LDIM + c];
#pragma unroll
  for (int t = 0; t < 8; ++t) ws += wsum[bi * 8 + t];
  out[e] = (ws > 0.f) ? (ps / ws) : 0.f;
}

extern "C" void kernel_launch(void* const* d_in, const int* in_sizes, int n_in,
                              void* d_out, int out_size, void* d_ws, size_t ws_size,
                              hipStream_t stream) {
  const float* x = (const float*)d_in[0];
  const float* W1 = (const float*)d_in[1];
  const float* W2 = (const float*)d_in[2];
  const int* ids = (const int*)d_in[3];
  const void* pad = d_in[4]; // bool ABI detected at runtime
  float* out = (float*)d_out;

  char* ws = (char*)d_ws;
  short* wfrag = (short*)ws;                        // 131072 B
  float* A = (float*)(ws + 131072);                 // 262144 B
  unsigned int* gmax = (unsigned int*)(ws + 393216);// 512 B
  float* wsum = (float*)(ws + 393728);              // 4096 B
  int* flag = (int*)(ws + 397824);                  // 4 B (pad to 397952)
  float* partial = (float*)(ws + 397952);           // 4194304 B (1024*2*512*4)

  hipLaunchKernelGGL(k0_wfrag, dim3(32), dim3(256), 0, stream,
                     W1, wfrag, (const unsigned int*)pad, flag, gmax);
  hipLaunchKernelGGL(k1_scores, dim3((BATCH * NTOK) / 128), dim3(512), 0, stream,
                     x, wfrag, W2, ids, pad, flag, A, gmax);
  hipLaunchKernelGGL(k3_pool, dim3(BATCH * NQ * NSEG), dim3(256), 0, stream,
                     x, A, ids, pad, flag, gmax, partial, wsum);
  hipLaunchKernelGGL(k4_reduce, dim3((BATCH * NQ * LDIM) / 256), dim3(256), 0, stream,
                     partial, wsum, out);
}